// Round 9
// baseline (349.356 us; speedup 1.0000x reference)
//
#include <hip/hip_runtime.h>
#include <hip/hip_bf16.h>
#include <stdint.h>

// ---------------------------------------------------------------------------
// E=64 H=64 PRE1=512 BNK=1024 S=256 P=16 B=4096. Attention branch dead
// (softmax over size-1 axis == 1). Decomposition (rel is rank-2):
//   Z1[s,i,j,k] = rx*MX[k] + ry*MY[k] + HH[16s+j][k];  Y1 = relu(Z1)
//   out = maxpool_j relu(bn2(Y1 @ Wp2))
// v8: Y1 MATERIALIZED ONCE per WG in LDS (bf16, swizzled) -- construction is
//     off the K-loop critical path (v4-v7 all VALU/latency-bound on per-ks
//     A-frag construction, MfmaUtil pinned at 17-24%). K-loop is then a pure
//     GEMM: A from LDS (ds_read_b128), B streamed from L2 (global, ig-pair
//     L1 sharing), 32 MFMA per wave-ks, ZERO barriers. WG=(scene,i-half),
//     512 thr = 8 waves = (ig:4 rowtiles) x (ng:16 nt in 2 chunks).
//     HH computed in-kernel via MFMA from packed W1b. LDS 148 KB, 1 WG/CU.
// ---------------------------------------------------------------------------

typedef __bf16 bf16x8 __attribute__((ext_vector_type(8)));
typedef __bf16 bf16x2 __attribute__((ext_vector_type(2)));
typedef float  f32x4  __attribute__((ext_vector_type(4)));
typedef float  f32x2  __attribute__((ext_vector_type(2)));

// workspace layout (bytes)
#define BP2_OFF 0u          // packed Wp2: [nt(64)][ks(16)][l(64)]*16B = 1 MB
#define BP1_OFF 1048576u    // packed W1b (Wp1 rows 64..127): [nt(32)][kb(2)][l]*16B = 64 KB
#define MX_OFF  1114112u    // 512 f32
#define MY_OFF  1116160u
#define CB_OFF  1118208u
#define SH_OFF  1120256u
#define A2_OFF  1122304u    // 1024 f32
#define C2_OFF  1126400u

// mm2 LDS layout (bytes)
#define Y1_LDS  0           // bf16 [128 r][512 k], row stride 1024 B, swizzle ^((r&7)<<4)
#define HH_LDS  131072      // bf16 [16 j][512 k], row stride 1024 B
#define MX_LDS  147456      // f32[512]
#define MY_LDS  149504      // f32[512]
#define PF_LDS  151552      // f32[32]
#define LDS_SZ  151680      // 148.1 KB

__device__ __forceinline__ unsigned short f2bf(float f) {
    union { float f; unsigned u; } c; c.f = f;
    unsigned u = c.u;
    return (unsigned short)((u + 0x7fffu + ((u >> 16) & 1u)) >> 16);
}
__device__ __forceinline__ float bfbits2f(unsigned hi) {
    union { unsigned u; float f; } c; c.u = hi; return c.f;
}
__device__ __forceinline__ unsigned pk_bf16(float a, float b) {
#if __has_builtin(__builtin_amdgcn_cvt_pk_bf16_f32)
    bf16x2 p = __builtin_amdgcn_cvt_pk_bf16_f32(a, b);
    union { bf16x2 v; unsigned u; } c; c.v = p; return c.u;
#else
    return (unsigned)f2bf(a) | ((unsigned)f2bf(b) << 16);
#endif
}

// ---------------------------------------------------------------------------
// prep_pack: blocks 0..255 pack Wp2, 256..271 pack W1b (LDS transpose,
// coalesced float4 reads), 272..273 fold k-consts, 274..277 fold A2/C2.
// B-frag (16x16x32): lane l holds B[k=kb*32+(l>>4)*8+j][n=nt*16+(l&15)],
// packed at ((nt*KB+kb)*64+l)*16 bytes.
// ---------------------------------------------------------------------------
__global__ __launch_bounds__(256) void prep_pack_kernel(
    const float* __restrict__ Wsp,  const float* __restrict__ bsp,
    const float* __restrict__ Wp1,  const float* __restrict__ bp1,
    const float* __restrict__ gp1,  const float* __restrict__ btp1,
    const float* __restrict__ mp1,  const float* __restrict__ vp1,
    const float* __restrict__ Wp2,  const float* __restrict__ bp2,
    const float* __restrict__ gp2,  const float* __restrict__ btp2,
    const float* __restrict__ mp2,  const float* __restrict__ vp2,
    unsigned char* __restrict__ ws)
{
    __shared__ float tile[32 * 65];
    const int blk = blockIdx.x, t = threadIdx.x;

    if (blk < 272) {
        const float* src; int ncols, kb, ng, KB; unsigned outoff;
        if (blk < 256) { kb = blk >> 4; ng = blk & 15; src = Wp2; ncols = 1024; KB = 16; outoff = BP2_OFF; }
        else { int b2 = blk - 256; kb = b2 >> 3; ng = b2 & 7; src = Wp1 + 64 * 512; ncols = 512; KB = 2; outoff = BP1_OFF; }
        const int k0 = kb * 32, n0 = ng * 64;
        #pragma unroll
        for (int it = 0; it < 2; ++it) {
            int c = t + it * 256;
            int r = c >> 4, c4 = c & 15;
            float4 v = *(const float4*)(src + (k0 + r) * ncols + n0 + c4 * 4);
            tile[r * 65 + c4 * 4 + 0] = v.x;
            tile[r * 65 + c4 * 4 + 1] = v.y;
            tile[r * 65 + c4 * 4 + 2] = v.z;
            tile[r * 65 + c4 * 4 + 3] = v.w;
        }
        __syncthreads();
        int ntl = t >> 6, l = t & 63;
        int nl = ntl * 16 + (l & 15), kl = (l >> 4) * 8;
        uint4 o;
        o.x = pk_bf16(tile[(kl + 0) * 65 + nl], tile[(kl + 1) * 65 + nl]);
        o.y = pk_bf16(tile[(kl + 2) * 65 + nl], tile[(kl + 3) * 65 + nl]);
        o.z = pk_bf16(tile[(kl + 4) * 65 + nl], tile[(kl + 5) * 65 + nl]);
        o.w = pk_bf16(tile[(kl + 6) * 65 + nl], tile[(kl + 7) * 65 + nl]);
        ((uint4*)(ws + outoff))[((ng * 4 + ntl) * KB + kb) * 64 + l] = o;
    } else if (blk < 274) {
        int k = (blk - 272) * 256 + t;
        float a1 = gp1[k] * rsqrtf(vp1[k] + 1e-5f);
        float mx = 0.f, my = 0.f, cb = 0.f;
        for (int e = 0; e < 64; ++e) {
            float wv = Wp1[e * 512 + k];
            mx = fmaf(Wsp[e],      wv, mx);
            my = fmaf(Wsp[64 + e], wv, my);
            cb = fmaf(bsp[e],      wv, cb);
        }
        ((float*)(ws + MX_OFF))[k] = 0.05f * a1 * mx;
        ((float*)(ws + MY_OFF))[k] = 0.05f * a1 * my;
        ((float*)(ws + CB_OFF))[k] = 0.05f * a1 * cb + (bp1[k] - mp1[k]) * a1 + btp1[k];
        ((float*)(ws + SH_OFF))[k] = 0.05f * a1;
    } else {
        int n = (blk - 274) * 256 + t;
        float a = gp2[n] * rsqrtf(vp2[n] + 1e-5f);
        ((float*)(ws + A2_OFF))[n] = a;
        ((float*)(ws + C2_OFF))[n] = btp2[n] + (bp2[n] - mp2[n]) * a;
    }
}

// ---------------------------------------------------------------------------
// mm2 v8: WG = (scene s, i-half ih). 512 thr = 8 waves.
// Phase A (1 barrier): stage MX/MY/posf; HH[16x512] via 8 MFMA/wave from
//   h x packed W1b; write HH bf16 to LDS.
// Phase B (1 barrier): construct Y1[128x512] bf16 into LDS. Thread =
//   (i2,j,kc): 4 i x 32 k for one j -> HH/MX/MY reads amortized 4x.
// Phase C (no barriers): pure GEMM. Wave (ig,ng) = 4 rowtiles x 16 nt
//   (2 chunks of 8). Per ks: 4 ds_read_b128 A + 8 global B (2-stage
//   rotation) + 32 MFMA. Epilogue: bn2+relu+maxpool_j (regs+shfl), store.
// ---------------------------------------------------------------------------
__global__ __launch_bounds__(512, 2) void mm2_kernel(
    const float* __restrict__ hst,
    const float* __restrict__ epos,
    const unsigned char* __restrict__ ws,
    float* __restrict__ out)
{
    __shared__ __align__(16) unsigned char smem[LDS_SZ];
    float* posf = (float*)(smem + PF_LDS);

    const int s   = blockIdx.x >> 1;     // 256 scenes
    const int ih  = blockIdx.x & 1;      // i-half
    const int tid = threadIdx.x;
    const int w    = tid >> 6;           // 0..7
    const int l    = tid & 63;
    const int quad = l >> 4;
    const int jl   = l & 15;

    // ---- Phase A: stage MX/MY/posf + HH via MFMA ----
    ((float*)(smem + MX_LDS))[tid] = ((const float*)(ws + MX_OFF))[tid];
    ((float*)(smem + MY_LDS))[tid] = ((const float*)(ws + MY_OFF))[tid];
    if (tid < 32) posf[tid] = epos[s * 32 + tid];
    {
        union { unsigned u[4]; bf16x8 v; } afh[2];
        #pragma unroll
        for (int kb = 0; kb < 2; ++kb) {
            const float4* hp = (const float4*)(hst + (s * 16 + jl) * 64 + kb * 32 + quad * 8);
            float4 v0 = hp[0], v1 = hp[1];
            afh[kb].u[0] = pk_bf16(v0.x, v0.y);
            afh[kb].u[1] = pk_bf16(v0.z, v0.w);
            afh[kb].u[2] = pk_bf16(v1.x, v1.y);
            afh[kb].u[3] = pk_bf16(v1.z, v1.w);
        }
        const f32x4 fz = {0.f, 0.f, 0.f, 0.f};
        f32x4 acch[4] = {fz, fz, fz, fz};     // wave w -> k-cols w*64..+63
        #pragma unroll
        for (int kb = 0; kb < 2; ++kb) {
            #pragma unroll
            for (int ct = 0; ct < 4; ++ct) {
                bf16x8 bfr = *(const bf16x8*)(ws + BP1_OFF + ((((w * 4 + ct) * 2 + kb) * 64 + l) << 4));
                acch[ct] = __builtin_amdgcn_mfma_f32_16x16x32_bf16(afh[kb].v, bfr, acch[ct], 0, 0, 0);
            }
        }
        const float* SHg = (const float*)(ws + SH_OFF);
        const float* CBg = (const float*)(ws + CB_OFF);
        #pragma unroll
        for (int ct = 0; ct < 4; ++ct) {
            int col = (w * 4 + ct) * 16 + jl;        // k index
            float sh = SHg[col], cb = CBg[col];
            #pragma unroll
            for (int reg = 0; reg < 4; ++reg) {
                int j = quad * 4 + reg;
                float hv = fmaf(acch[ct][reg], sh, cb);
                *(unsigned short*)(smem + HH_LDS + j * 1024 + col * 2) = f2bf(hv);
            }
        }
    }
    __syncthreads();

    // ---- Phase B: construct Y1 (bf16, swizzled) ----
    {
        const int i2 = tid >> 8;           // 0..1  (4 i each)
        const int j  = (tid >> 4) & 15;
        const int kc = tid & 15;           // k0 = kc*32
        const int swz = (j & 7) << 4;
        float rx[4], ry[4];
        float pjx = posf[j * 2], pjy = posf[j * 2 + 1];
        #pragma unroll
        for (int ii = 0; ii < 4; ++ii) {
            int ig_ = ih * 8 + i2 * 4 + ii;
            rx[ii] = pjx - posf[ig_ * 2];
            ry[ii] = pjy - posf[ig_ * 2 + 1];
        }
        const f32x2 zero2 = {0.f, 0.f};
        #pragma unroll
        for (int kk = 0; kk < 4; ++kk) {
            int k = kc * 32 + kk * 8;
            uint4 hh8 = *(const uint4*)(smem + HH_LDS + j * 1024 + k * 2);
            f32x4 mx0 = *(const f32x4*)(smem + MX_LDS + k * 4);
            f32x4 mx1 = *(const f32x4*)(smem + MX_LDS + k * 4 + 16);
            f32x4 my0 = *(const f32x4*)(smem + MY_LDS + k * 4);
            f32x4 my1 = *(const f32x4*)(smem + MY_LDS + k * 4 + 16);
            f32x2 mxp[4] = { {mx0[0],mx0[1]}, {mx0[2],mx0[3]}, {mx1[0],mx1[1]}, {mx1[2],mx1[3]} };
            f32x2 myp[4] = { {my0[0],my0[1]}, {my0[2],my0[3]}, {my1[0],my1[1]}, {my1[2],my1[3]} };
            f32x2 hhp[4];
            hhp[0][0] = bfbits2f(hh8.x << 16); hhp[0][1] = bfbits2f(hh8.x & 0xffff0000u);
            hhp[1][0] = bfbits2f(hh8.y << 16); hhp[1][1] = bfbits2f(hh8.y & 0xffff0000u);
            hhp[2][0] = bfbits2f(hh8.z << 16); hhp[2][1] = bfbits2f(hh8.z & 0xffff0000u);
            hhp[3][0] = bfbits2f(hh8.w << 16); hhp[3][1] = bfbits2f(hh8.w & 0xffff0000u);
            #pragma unroll
            for (int ii = 0; ii < 4; ++ii) {
                f32x2 rx2 = { rx[ii], rx[ii] };
                f32x2 ry2 = { ry[ii], ry[ii] };
                uint4 o;
                unsigned uu[4];
                #pragma unroll
                for (int p = 0; p < 4; ++p) {
                    f32x2 tt = __builtin_elementwise_fma(ry2, myp[p], hhp[p]);
                    tt = __builtin_elementwise_fma(rx2, mxp[p], tt);
                    tt = __builtin_elementwise_max(tt, zero2);
                    uu[p] = pk_bf16(tt[0], tt[1]);
                }
                o.x = uu[0]; o.y = uu[1]; o.z = uu[2]; o.w = uu[3];
                int r = (i2 * 4 + ii) * 16 + j;
                *(uint4*)(smem + Y1_LDS + r * 1024 + ((k * 2) ^ swz)) = o;
            }
        }
    }
    __syncthreads();

    // ---- Phase C: pure GEMM, no barriers ----
    const int ig = w & 1;                 // rowtiles i_local = ig*4 .. +3
    const int ng = w >> 1;                // nt group: 16 nt in 2 chunks of 8
    const unsigned char* bws = ws + BP2_OFF;
    const float* A2 = (const float*)(ws + A2_OFF);
    const float* C2 = (const float*)(ws + C2_OFF);
    const f32x4 fzero = {0.f, 0.f, 0.f, 0.f};

    #pragma unroll 1
    for (int chunk = 0; chunk < 2; ++chunk) {
        const int ntbase = ng * 16 + chunk * 8;
        f32x4 acc[4][8];
        #pragma unroll
        for (int rt = 0; rt < 4; ++rt)
            #pragma unroll
            for (int ct = 0; ct < 8; ++ct) acc[rt][ct] = fzero;

        bf16x8 bcur[8], bnxt[8];
        #pragma unroll
        for (int ct = 0; ct < 8; ++ct)
            bcur[ct] = *(const bf16x8*)(bws + ((((ntbase + ct) * 16 + 0) * 64 + l) << 4));

        #pragma unroll
        for (int ks = 0; ks < 16; ++ks) {
            if (ks < 15) {
                #pragma unroll
                for (int ct = 0; ct < 8; ++ct)
                    bnxt[ct] = *(const bf16x8*)(bws + ((((ntbase + ct) * 16 + ks + 1) * 64 + l) << 4));
            }
            bf16x8 af[4];
            #pragma unroll
            for (int rt = 0; rt < 4; ++rt) {
                int r = (ig * 4 + rt) * 16 + jl;
                int off = (ks * 64 + quad * 16) ^ ((jl & 7) << 4);
                af[rt] = *(const bf16x8*)(smem + Y1_LDS + r * 1024 + off);
            }
            #pragma unroll
            for (int rt = 0; rt < 4; ++rt)
                #pragma unroll
                for (int ct = 0; ct < 8; ++ct)
                    acc[rt][ct] = __builtin_amdgcn_mfma_f32_16x16x32_bf16(af[rt], bcur[ct], acc[rt][ct], 0, 0, 0);
            if (ks < 15) {
                #pragma unroll
                for (int ct = 0; ct < 8; ++ct) bcur[ct] = bnxt[ct];
            }
        }

        // epilogue: bn2 + relu, maxpool over j (D rows), store fp32
        #pragma unroll
        for (int ct = 0; ct < 8; ++ct) {
            int col = (ntbase + ct) * 16 + jl;
            float a2 = A2[col], c2 = C2[col];
            #pragma unroll
            for (int rt = 0; rt < 4; ++rt) {
                float v0 = fmaxf(fmaf(acc[rt][ct][0], a2, c2), 0.f);
                float v1 = fmaxf(fmaf(acc[rt][ct][1], a2, c2), 0.f);
                float v2 = fmaxf(fmaf(acc[rt][ct][2], a2, c2), 0.f);
                float v3 = fmaxf(fmaf(acc[rt][ct][3], a2, c2), 0.f);
                float v = fmaxf(fmaxf(v0, v1), fmaxf(v2, v3));
                v = fmaxf(v, __shfl_xor(v, 16, 64));
                v = fmaxf(v, __shfl_xor(v, 32, 64));
                if (l < 16) {
                    int orow = s * 16 + ih * 8 + ig * 4 + rt;
                    __builtin_nontemporal_store(v, &out[orow * 1024 + col]);
                }
            }
        }
    }
}

extern "C" void kernel_launch(void* const* d_in, const int* in_sizes, int n_in,
                              void* d_out, int out_size, void* d_ws, size_t ws_size,
                              hipStream_t stream) {
    const float* hst  = (const float*)d_in[0];
    const float* epos = (const float*)d_in[1];
    const float* Wsp  = (const float*)d_in[4];
    const float* bsp  = (const float*)d_in[5];
    const float* Wp1  = (const float*)d_in[20];
    const float* bp1  = (const float*)d_in[21];
    const float* gp1  = (const float*)d_in[22];
    const float* btp1 = (const float*)d_in[23];
    const float* mp1  = (const float*)d_in[24];
    const float* vp1  = (const float*)d_in[25];
    const float* Wp2  = (const float*)d_in[26];
    const float* bp2  = (const float*)d_in[27];
    const float* gp2  = (const float*)d_in[28];
    const float* btp2 = (const float*)d_in[29];
    const float* mp2  = (const float*)d_in[30];
    const float* vp2  = (const float*)d_in[31];
    unsigned char* ws = (unsigned char*)d_ws;
    float* out = (float*)d_out;

    // 256 (Wp2 pack) + 16 (W1b pack) + 2 (k-consts) + 4 (A2/C2) = 278 blocks
    prep_pack_kernel<<<278, 256, 0, stream>>>(Wsp, bsp, Wp1, bp1, gp1, btp1, mp1, vp1,
                                              Wp2, bp2, gp2, btp2, mp2, vp2, ws);
    // 256 scenes x 2 i-halves, 512 threads (8 waves)
    mm2_kernel<<<512, 512, 0, stream>>>(hst, epos, ws, out);
}

// Round 10
// 198.419 us; speedup vs baseline: 1.7607x; 1.7607x over previous
//
#include <hip/hip_runtime.h>
#include <hip/hip_bf16.h>
#include <stdint.h>

// ---------------------------------------------------------------------------
// E=64 H=64 PRE1=512 BNK=1024 S=256 P=16 B=4096. Attention branch dead
// (softmax over size-1 axis == 1). Decomposition (rel is rank-2):
//   Z1[s,i,j,k] = rx*MX[k] + ry*MY[k] + HH[16s+j][k];  Y1 = relu(Z1)
//   out = maxpool_j relu(bn2(Y1 @ Wp2))
// v9: v8 minus the register explosion. v8's `#pragma unroll` (full 16x) on
//     the ks loop + 8-wide B rotation spilled ~230 regs/thread (VGPR=128
//     maxed, 262 MB scratch writes, L2 blown -> 241 MB HBM refetch).
//     v9: `#pragma unroll 1` ks loop, single-stage bcur/bnxt rotation
//     (~228 live regs under the 256 budget), and a kc-spreading Y1 swizzle
//     (c16 ^ (c16>>3) ^ (r&7)) that fixes Phase-B's 8-way write conflicts.
//     Structure unchanged: Y1 materialized once in LDS; Phase-C K-loop is a
//     pure GEMM (4 ds_read_b128 A + 8 global B + 32 MFMA per wave-ks, zero
//     barriers). LDS 148 KB, 1 WG/CU, 8 waves.
// ---------------------------------------------------------------------------

typedef __bf16 bf16x8 __attribute__((ext_vector_type(8)));
typedef __bf16 bf16x2 __attribute__((ext_vector_type(2)));
typedef float  f32x4  __attribute__((ext_vector_type(4)));
typedef float  f32x2  __attribute__((ext_vector_type(2)));

// workspace layout (bytes)
#define BP2_OFF 0u          // packed Wp2: [nt(64)][ks(16)][l(64)]*16B = 1 MB
#define BP1_OFF 1048576u    // packed W1b (Wp1 rows 64..127): [nt(32)][kb(2)][l]*16B = 64 KB
#define MX_OFF  1114112u    // 512 f32
#define MY_OFF  1116160u
#define CB_OFF  1118208u
#define SH_OFF  1120256u
#define A2_OFF  1122304u    // 1024 f32
#define C2_OFF  1126400u

// mm2 LDS layout (bytes)
#define Y1_LDS  0           // bf16 [128 r][512 k], row stride 1024 B, swizzled (see y1off)
#define HH_LDS  131072      // bf16 [16 j][512 k], row stride 1024 B
#define MX_LDS  147456      // f32[512]
#define MY_LDS  149504      // f32[512]
#define PF_LDS  151552      // f32[32]
#define LDS_SZ  151680      // 148.1 KB

__device__ __forceinline__ unsigned short f2bf(float f) {
    union { float f; unsigned u; } c; c.f = f;
    unsigned u = c.u;
    return (unsigned short)((u + 0x7fffu + ((u >> 16) & 1u)) >> 16);
}
__device__ __forceinline__ float bfbits2f(unsigned hi) {
    union { unsigned u; float f; } c; c.u = hi; return c.f;
}
__device__ __forceinline__ unsigned pk_bf16(float a, float b) {
#if __has_builtin(__builtin_amdgcn_cvt_pk_bf16_f32)
    bf16x2 p = __builtin_amdgcn_cvt_pk_bf16_f32(a, b);
    union { bf16x2 v; unsigned u; } c; c.v = p; return c.u;
#else
    return (unsigned)f2bf(a) | ((unsigned)f2bf(b) << 16);
#endif
}
// Y1 address: row r (0..127), 16-byte chunk index c16 (0..63).
// Swizzle spreads both the A-read pattern (quad) and the Phase-B write
// pattern (kc, via c16>>3) across banksets; bijective in c16 per row.
__device__ __forceinline__ int y1off(int r, int c16) {
    return r * 1024 + (((c16 ^ (c16 >> 3) ^ (r & 7)) & 63) << 4);
}

// ---------------------------------------------------------------------------
// prep_pack: blocks 0..255 pack Wp2, 256..271 pack W1b (LDS transpose,
// coalesced float4 reads), 272..273 fold k-consts, 274..277 fold A2/C2.
// B-frag (16x16x32): lane l holds B[k=kb*32+(l>>4)*8+j][n=nt*16+(l&15)],
// packed at ((nt*KB+kb)*64+l)*16 bytes.
// ---------------------------------------------------------------------------
__global__ __launch_bounds__(256) void prep_pack_kernel(
    const float* __restrict__ Wsp,  const float* __restrict__ bsp,
    const float* __restrict__ Wp1,  const float* __restrict__ bp1,
    const float* __restrict__ gp1,  const float* __restrict__ btp1,
    const float* __restrict__ mp1,  const float* __restrict__ vp1,
    const float* __restrict__ Wp2,  const float* __restrict__ bp2,
    const float* __restrict__ gp2,  const float* __restrict__ btp2,
    const float* __restrict__ mp2,  const float* __restrict__ vp2,
    unsigned char* __restrict__ ws)
{
    __shared__ float tile[32 * 65];
    const int blk = blockIdx.x, t = threadIdx.x;

    if (blk < 272) {
        const float* src; int ncols, kb, ng, KB; unsigned outoff;
        if (blk < 256) { kb = blk >> 4; ng = blk & 15; src = Wp2; ncols = 1024; KB = 16; outoff = BP2_OFF; }
        else { int b2 = blk - 256; kb = b2 >> 3; ng = b2 & 7; src = Wp1 + 64 * 512; ncols = 512; KB = 2; outoff = BP1_OFF; }
        const int k0 = kb * 32, n0 = ng * 64;
        #pragma unroll
        for (int it = 0; it < 2; ++it) {
            int c = t + it * 256;
            int r = c >> 4, c4 = c & 15;
            float4 v = *(const float4*)(src + (k0 + r) * ncols + n0 + c4 * 4);
            tile[r * 65 + c4 * 4 + 0] = v.x;
            tile[r * 65 + c4 * 4 + 1] = v.y;
            tile[r * 65 + c4 * 4 + 2] = v.z;
            tile[r * 65 + c4 * 4 + 3] = v.w;
        }
        __syncthreads();
        int ntl = t >> 6, l = t & 63;
        int nl = ntl * 16 + (l & 15), kl = (l >> 4) * 8;
        uint4 o;
        o.x = pk_bf16(tile[(kl + 0) * 65 + nl], tile[(kl + 1) * 65 + nl]);
        o.y = pk_bf16(tile[(kl + 2) * 65 + nl], tile[(kl + 3) * 65 + nl]);
        o.z = pk_bf16(tile[(kl + 4) * 65 + nl], tile[(kl + 5) * 65 + nl]);
        o.w = pk_bf16(tile[(kl + 6) * 65 + nl], tile[(kl + 7) * 65 + nl]);
        ((uint4*)(ws + outoff))[((ng * 4 + ntl) * KB + kb) * 64 + l] = o;
    } else if (blk < 274) {
        int k = (blk - 272) * 256 + t;
        float a1 = gp1[k] * rsqrtf(vp1[k] + 1e-5f);
        float mx = 0.f, my = 0.f, cb = 0.f;
        for (int e = 0; e < 64; ++e) {
            float wv = Wp1[e * 512 + k];
            mx = fmaf(Wsp[e],      wv, mx);
            my = fmaf(Wsp[64 + e], wv, my);
            cb = fmaf(bsp[e],      wv, cb);
        }
        ((float*)(ws + MX_OFF))[k] = 0.05f * a1 * mx;
        ((float*)(ws + MY_OFF))[k] = 0.05f * a1 * my;
        ((float*)(ws + CB_OFF))[k] = 0.05f * a1 * cb + (bp1[k] - mp1[k]) * a1 + btp1[k];
        ((float*)(ws + SH_OFF))[k] = 0.05f * a1;
    } else {
        int n = (blk - 274) * 256 + t;
        float a = gp2[n] * rsqrtf(vp2[n] + 1e-5f);
        ((float*)(ws + A2_OFF))[n] = a;
        ((float*)(ws + C2_OFF))[n] = btp2[n] + (bp2[n] - mp2[n]) * a;
    }
}

// ---------------------------------------------------------------------------
// mm2 v9: WG = (scene s, i-half ih). 512 thr = 8 waves.
// Phase A (1 barrier): stage MX/MY/posf; HH[16x512] via 8 MFMA/wave.
// Phase B (1 barrier): construct Y1[128x512] bf16 into LDS (amortized 4x).
// Phase C (no barriers): pure GEMM, wave (ig,ng) = 4 rowtiles x 16 nt in
//   2 chunks of 8; ks loop unroll=1 with single-stage B rotation.
// ---------------------------------------------------------------------------
__global__ __launch_bounds__(512, 2) void mm2_kernel(
    const float* __restrict__ hst,
    const float* __restrict__ epos,
    const unsigned char* __restrict__ ws,
    float* __restrict__ out)
{
    __shared__ __align__(16) unsigned char smem[LDS_SZ];
    float* posf = (float*)(smem + PF_LDS);

    const int s   = blockIdx.x >> 1;     // 256 scenes
    const int ih  = blockIdx.x & 1;      // i-half
    const int tid = threadIdx.x;
    const int w    = tid >> 6;           // 0..7
    const int l    = tid & 63;
    const int quad = l >> 4;
    const int jl   = l & 15;

    // ---- Phase A: stage MX/MY/posf + HH via MFMA ----
    ((float*)(smem + MX_LDS))[tid] = ((const float*)(ws + MX_OFF))[tid];
    ((float*)(smem + MY_LDS))[tid] = ((const float*)(ws + MY_OFF))[tid];
    if (tid < 32) posf[tid] = epos[s * 32 + tid];
    {
        union { unsigned u[4]; bf16x8 v; } afh[2];
        #pragma unroll
        for (int kb = 0; kb < 2; ++kb) {
            const float4* hp = (const float4*)(hst + (s * 16 + jl) * 64 + kb * 32 + quad * 8);
            float4 v0 = hp[0], v1 = hp[1];
            afh[kb].u[0] = pk_bf16(v0.x, v0.y);
            afh[kb].u[1] = pk_bf16(v0.z, v0.w);
            afh[kb].u[2] = pk_bf16(v1.x, v1.y);
            afh[kb].u[3] = pk_bf16(v1.z, v1.w);
        }
        const f32x4 fz = {0.f, 0.f, 0.f, 0.f};
        f32x4 acch[4] = {fz, fz, fz, fz};     // wave w -> k-cols w*64..+63
        #pragma unroll
        for (int kb = 0; kb < 2; ++kb) {
            #pragma unroll
            for (int ct = 0; ct < 4; ++ct) {
                bf16x8 bfr = *(const bf16x8*)(ws + BP1_OFF + ((((w * 4 + ct) * 2 + kb) * 64 + l) << 4));
                acch[ct] = __builtin_amdgcn_mfma_f32_16x16x32_bf16(afh[kb].v, bfr, acch[ct], 0, 0, 0);
            }
        }
        const float* SHg = (const float*)(ws + SH_OFF);
        const float* CBg = (const float*)(ws + CB_OFF);
        #pragma unroll
        for (int ct = 0; ct < 4; ++ct) {
            int col = (w * 4 + ct) * 16 + jl;        // k index
            float sh = SHg[col], cb = CBg[col];
            #pragma unroll
            for (int reg = 0; reg < 4; ++reg) {
                int j = quad * 4 + reg;
                float hv = fmaf(acch[ct][reg], sh, cb);
                *(unsigned short*)(smem + HH_LDS + j * 1024 + col * 2) = f2bf(hv);
            }
        }
    }
    __syncthreads();

    // ---- Phase B: construct Y1 (bf16, swizzled) ----
    {
        const int i2 = tid >> 8;           // 0..1  (4 i each)
        const int j  = (tid >> 4) & 15;
        const int kc = tid & 15;           // k0 = kc*32
        float rx[4], ry[4];
        float pjx = posf[j * 2], pjy = posf[j * 2 + 1];
        #pragma unroll
        for (int ii = 0; ii < 4; ++ii) {
            int ig_ = ih * 8 + i2 * 4 + ii;
            rx[ii] = pjx - posf[ig_ * 2];
            ry[ii] = pjy - posf[ig_ * 2 + 1];
        }
        const f32x2 zero2 = {0.f, 0.f};
        #pragma unroll
        for (int kk = 0; kk < 4; ++kk) {
            int k = kc * 32 + kk * 8;
            uint4 hh8 = *(const uint4*)(smem + HH_LDS + j * 1024 + k * 2);
            f32x4 mx0 = *(const f32x4*)(smem + MX_LDS + k * 4);
            f32x4 mx1 = *(const f32x4*)(smem + MX_LDS + k * 4 + 16);
            f32x4 my0 = *(const f32x4*)(smem + MY_LDS + k * 4);
            f32x4 my1 = *(const f32x4*)(smem + MY_LDS + k * 4 + 16);
            f32x2 mxp[4] = { {mx0[0],mx0[1]}, {mx0[2],mx0[3]}, {mx1[0],mx1[1]}, {mx1[2],mx1[3]} };
            f32x2 myp[4] = { {my0[0],my0[1]}, {my0[2],my0[3]}, {my1[0],my1[1]}, {my1[2],my1[3]} };
            f32x2 hhp[4];
            hhp[0][0] = bfbits2f(hh8.x << 16); hhp[0][1] = bfbits2f(hh8.x & 0xffff0000u);
            hhp[1][0] = bfbits2f(hh8.y << 16); hhp[1][1] = bfbits2f(hh8.y & 0xffff0000u);
            hhp[2][0] = bfbits2f(hh8.z << 16); hhp[2][1] = bfbits2f(hh8.z & 0xffff0000u);
            hhp[3][0] = bfbits2f(hh8.w << 16); hhp[3][1] = bfbits2f(hh8.w & 0xffff0000u);
            #pragma unroll
            for (int ii = 0; ii < 4; ++ii) {
                f32x2 rx2 = { rx[ii], rx[ii] };
                f32x2 ry2 = { ry[ii], ry[ii] };
                uint4 o;
                unsigned uu[4];
                #pragma unroll
                for (int p = 0; p < 4; ++p) {
                    f32x2 tt = __builtin_elementwise_fma(ry2, myp[p], hhp[p]);
                    tt = __builtin_elementwise_fma(rx2, mxp[p], tt);
                    tt = __builtin_elementwise_max(tt, zero2);
                    uu[p] = pk_bf16(tt[0], tt[1]);
                }
                o.x = uu[0]; o.y = uu[1]; o.z = uu[2]; o.w = uu[3];
                int r = (i2 * 4 + ii) * 16 + j;
                *(uint4*)(smem + Y1_LDS + y1off(r, kc * 4 + kk)) = o;
            }
        }
    }
    __syncthreads();

    // ---- Phase C: pure GEMM, no barriers ----
    const int ig = w & 1;                 // rowtiles i_local = ig*4 .. +3
    const int ng = w >> 1;                // nt group: 16 nt in 2 chunks of 8
    const float* A2 = (const float*)(ws + A2_OFF);
    const float* C2 = (const float*)(ws + C2_OFF);
    const f32x4 fzero = {0.f, 0.f, 0.f, 0.f};

    #pragma unroll 1
    for (int chunk = 0; chunk < 2; ++chunk) {
        const int ntbase = ng * 16 + chunk * 8;
        const unsigned char* bbase = ws + BP2_OFF + (((size_t)(ntbase * 16) * 64 + l) << 4);
        // stride per nt = 16384 B, per ks = 1024 B
        f32x4 acc[4][8];
        #pragma unroll
        for (int rt = 0; rt < 4; ++rt)
            #pragma unroll
            for (int ct = 0; ct < 8; ++ct) acc[rt][ct] = fzero;

        bf16x8 bcur[8];
        #pragma unroll
        for (int ct = 0; ct < 8; ++ct)
            bcur[ct] = *(const bf16x8*)(bbase + ct * 16384);

        #pragma unroll 1
        for (int ks = 0; ks < 16; ++ks) {
            bf16x8 af[4];
            #pragma unroll
            for (int rt = 0; rt < 4; ++rt) {
                int r = (ig * 4 + rt) * 16 + jl;
                af[rt] = *(const bf16x8*)(smem + Y1_LDS + y1off(r, ks * 4 + quad));
            }
            bf16x8 bnxt[8];
            if (ks < 15) {
                #pragma unroll
                for (int ct = 0; ct < 8; ++ct)
                    bnxt[ct] = *(const bf16x8*)(bbase + (ks + 1) * 1024 + ct * 16384);
            }
            #pragma unroll
            for (int rt = 0; rt < 4; ++rt)
                #pragma unroll
                for (int ct = 0; ct < 8; ++ct)
                    acc[rt][ct] = __builtin_amdgcn_mfma_f32_16x16x32_bf16(af[rt], bcur[ct], acc[rt][ct], 0, 0, 0);
            if (ks < 15) {
                #pragma unroll
                for (int ct = 0; ct < 8; ++ct) bcur[ct] = bnxt[ct];
            }
        }

        // epilogue: bn2 + relu, maxpool over j (D rows), store fp32
        #pragma unroll
        for (int ct = 0; ct < 8; ++ct) {
            int col = (ntbase + ct) * 16 + jl;
            float a2 = A2[col], c2 = C2[col];
            #pragma unroll
            for (int rt = 0; rt < 4; ++rt) {
                float v0 = fmaxf(fmaf(acc[rt][ct][0], a2, c2), 0.f);
                float v1 = fmaxf(fmaf(acc[rt][ct][1], a2, c2), 0.f);
                float v2 = fmaxf(fmaf(acc[rt][ct][2], a2, c2), 0.f);
                float v3 = fmaxf(fmaf(acc[rt][ct][3], a2, c2), 0.f);
                float v = fmaxf(fmaxf(v0, v1), fmaxf(v2, v3));
                v = fmaxf(v, __shfl_xor(v, 16, 64));
                v = fmaxf(v, __shfl_xor(v, 32, 64));
                if (l < 16) {
                    int orow = s * 16 + ih * 8 + ig * 4 + rt;
                    __builtin_nontemporal_store(v, &out[orow * 1024 + col]);
                }
            }
        }
    }
}

extern "C" void kernel_launch(void* const* d_in, const int* in_sizes, int n_in,
                              void* d_out, int out_size, void* d_ws, size_t ws_size,
                              hipStream_t stream) {
    const float* hst  = (const float*)d_in[0];
    const float* epos = (const float*)d_in[1];
    const float* Wsp  = (const float*)d_in[4];
    const float* bsp  = (const float*)d_in[5];
    const float* Wp1  = (const float*)d_in[20];
    const float* bp1  = (const float*)d_in[21];
    const float* gp1  = (const float*)d_in[22];
    const float* btp1 = (const float*)d_in[23];
    const float* mp1  = (const float*)d_in[24];
    const float* vp1  = (const float*)d_in[25];
    const float* Wp2  = (const float*)d_in[26];
    const float* bp2  = (const float*)d_in[27];
    const float* gp2  = (const float*)d_in[28];
    const float* btp2 = (const float*)d_in[29];
    const float* mp2  = (const float*)d_in[30];
    const float* vp2  = (const float*)d_in[31];
    unsigned char* ws = (unsigned char*)d_ws;
    float* out = (float*)d_out;

    // 256 (Wp2 pack) + 16 (W1b pack) + 2 (k-consts) + 4 (A2/C2) = 278 blocks
    prep_pack_kernel<<<278, 256, 0, stream>>>(Wsp, bsp, Wp1, bp1, gp1, btp1, mp1, vp1,
                                              Wp2, bp2, gp2, btp2, mp2, vp2, ws);
    // 256 scenes x 2 i-halves, 512 threads (8 waves)
    mm2_kernel<<<512, 512, 0, stream>>>(hst, epos, ws, out);
}

// Round 11
// 196.662 us; speedup vs baseline: 1.7764x; 1.0089x over previous
//
#include <hip/hip_runtime.h>
#include <hip/hip_bf16.h>
#include <stdint.h>

// ---------------------------------------------------------------------------
// E=64 H=64 PRE1=512 BNK=1024 S=256 P=16 B=4096. Attention branch dead
// (softmax over size-1 axis == 1). Decomposition (rel is rank-2):
//   Z1[s,i,j,k] = rx*MX[k] + ry*MY[k] + HH[16s+j][k];  Y1 = relu(Z1)
//   out = maxpool_j relu(bn2(Y1 @ Wp2))
// v10: v9 with the per-ks issue overhead removed. v9's MfmaUtil 33% =
//   exactly the MFMA pipe work; the 2/3 idle was ~75 VALU inst/ks/wave
//   (32 = bcur/bnxt rotation movs, rest = XOR address math) serialized
//   against LDS/L2 latency at 2 waves/SIMD. v10:
//   (1) ks unrolled x2, alternating B reg sets -> zero rotation movs;
//   (2) BP2 repacked [ks][nt][l] -> B addr = base + ks*64K + ct*1024;
//   (3) A swizzle = c16 ^ (r&7) (conflict-free 8x8 bankgroup split) ->
//       A addr = base[rt] (^64 odd ks) + t*128;
//   (4) MX/MY/pos read from global in Phase B (kills same-bank LDS reads).
//   LDS = Y1 128K + HH 16K = 144 KB, 1 WG/CU, 8 waves, no K-loop barriers.
// ---------------------------------------------------------------------------

typedef __bf16 bf16x8 __attribute__((ext_vector_type(8)));
typedef __bf16 bf16x2 __attribute__((ext_vector_type(2)));
typedef float  f32x4  __attribute__((ext_vector_type(4)));
typedef float  f32x2  __attribute__((ext_vector_type(2)));

// workspace layout (bytes)
#define BP2_OFF 0u          // packed Wp2: [ks(16)][nt(64)][l(64)]*16B = 1 MB
#define BP1_OFF 1048576u    // packed W1b (Wp1 rows 64..127): [nt(32)][kb(2)][l]*16B = 64 KB
#define MX_OFF  1114112u    // 512 f32
#define MY_OFF  1116160u
#define CB_OFF  1118208u
#define SH_OFF  1120256u
#define A2_OFF  1122304u    // 1024 f32
#define C2_OFF  1126400u

// mm2 LDS layout (bytes)
#define Y1_LDS  0           // bf16 [128 r][512 k], row stride 1024 B, off = ((c16^(r&7))<<4)
#define HH_LDS  131072      // bf16 [16 j][512 k], row stride 1024 B
#define LDS_SZ  147456      // 144 KB

__device__ __forceinline__ unsigned short f2bf(float f) {
    union { float f; unsigned u; } c; c.f = f;
    unsigned u = c.u;
    return (unsigned short)((u + 0x7fffu + ((u >> 16) & 1u)) >> 16);
}
__device__ __forceinline__ float bfbits2f(unsigned hi) {
    union { unsigned u; float f; } c; c.u = hi; return c.f;
}
__device__ __forceinline__ unsigned pk_bf16(float a, float b) {
#if __has_builtin(__builtin_amdgcn_cvt_pk_bf16_f32)
    bf16x2 p = __builtin_amdgcn_cvt_pk_bf16_f32(a, b);
    union { bf16x2 v; unsigned u; } c; c.v = p; return c.u;
#else
    return (unsigned)f2bf(a) | ((unsigned)f2bf(b) << 16);
#endif
}
// Y1 address: row r (0..127), 16-byte chunk c16 (0..63).
__device__ __forceinline__ int y1off(int r, int c16) {
    return r * 1024 + ((c16 ^ (r & 7)) << 4);
}

// ---------------------------------------------------------------------------
// prep_pack: blocks 0..255 pack Wp2 ([ks][nt][l] order), 256..271 pack W1b,
// 272..273 fold k-consts, 274..277 fold A2/C2. All global reads coalesced.
// B-frag (16x16x32): lane l holds B[k=kb*32+(l>>4)*8+j][n=nt*16+(l&15)].
// ---------------------------------------------------------------------------
__global__ __launch_bounds__(256) void prep_pack_kernel(
    const float* __restrict__ Wsp,  const float* __restrict__ bsp,
    const float* __restrict__ Wp1,  const float* __restrict__ bp1,
    const float* __restrict__ gp1,  const float* __restrict__ btp1,
    const float* __restrict__ mp1,  const float* __restrict__ vp1,
    const float* __restrict__ Wp2,  const float* __restrict__ bp2,
    const float* __restrict__ gp2,  const float* __restrict__ btp2,
    const float* __restrict__ mp2,  const float* __restrict__ vp2,
    unsigned char* __restrict__ ws)
{
    __shared__ float tile[32 * 65];
    const int blk = blockIdx.x, t = threadIdx.x;

    if (blk < 272) {
        const float* src; int ncols, kb, ng;
        if (blk < 256) { kb = blk >> 4; ng = blk & 15; src = Wp2; ncols = 1024; }
        else { int b2 = blk - 256; kb = b2 >> 3; ng = b2 & 7; src = Wp1 + 64 * 512; ncols = 512; }
        const int k0 = kb * 32, n0 = ng * 64;
        #pragma unroll
        for (int it = 0; it < 2; ++it) {
            int c = t + it * 256;
            int r = c >> 4, c4 = c & 15;
            float4 v = *(const float4*)(src + (k0 + r) * ncols + n0 + c4 * 4);
            tile[r * 65 + c4 * 4 + 0] = v.x;
            tile[r * 65 + c4 * 4 + 1] = v.y;
            tile[r * 65 + c4 * 4 + 2] = v.z;
            tile[r * 65 + c4 * 4 + 3] = v.w;
        }
        __syncthreads();
        int ntl = t >> 6, l = t & 63;
        int nl = ntl * 16 + (l & 15), kl = (l >> 4) * 8;
        uint4 o;
        o.x = pk_bf16(tile[(kl + 0) * 65 + nl], tile[(kl + 1) * 65 + nl]);
        o.y = pk_bf16(tile[(kl + 2) * 65 + nl], tile[(kl + 3) * 65 + nl]);
        o.z = pk_bf16(tile[(kl + 4) * 65 + nl], tile[(kl + 5) * 65 + nl]);
        o.w = pk_bf16(tile[(kl + 6) * 65 + nl], tile[(kl + 7) * 65 + nl]);
        if (blk < 256) {
            // [ks][nt][l]
            ((uint4*)(ws + BP2_OFF))[(kb * 64 + ng * 4 + ntl) * 64 + l] = o;
        } else {
            // [nt][kb][l]
            ((uint4*)(ws + BP1_OFF))[((ng * 4 + ntl) * 2 + kb) * 64 + l] = o;
        }
    } else if (blk < 274) {
        int k = (blk - 272) * 256 + t;
        float a1 = gp1[k] * rsqrtf(vp1[k] + 1e-5f);
        float mx = 0.f, my = 0.f, cb = 0.f;
        for (int e = 0; e < 64; ++e) {
            float wv = Wp1[e * 512 + k];
            mx = fmaf(Wsp[e],      wv, mx);
            my = fmaf(Wsp[64 + e], wv, my);
            cb = fmaf(bsp[e],      wv, cb);
        }
        ((float*)(ws + MX_OFF))[k] = 0.05f * a1 * mx;
        ((float*)(ws + MY_OFF))[k] = 0.05f * a1 * my;
        ((float*)(ws + CB_OFF))[k] = 0.05f * a1 * cb + (bp1[k] - mp1[k]) * a1 + btp1[k];
        ((float*)(ws + SH_OFF))[k] = 0.05f * a1;
    } else {
        int n = (blk - 274) * 256 + t;
        float a = gp2[n] * rsqrtf(vp2[n] + 1e-5f);
        ((float*)(ws + A2_OFF))[n] = a;
        ((float*)(ws + C2_OFF))[n] = btp2[n] + (bp2[n] - mp2[n]) * a;
    }
}

// ---------------------------------------------------------------------------
// mm2 v10: WG = (scene s, i-half ih). 512 thr = 8 waves.
// Phase A (1 barrier): HH[16x512] via 8 MFMA/wave from h x packed W1b.
// Phase B (1 barrier): construct Y1[128x512] bf16 (MX/MY/pos from global).
// Phase C (no barriers): pure GEMM, wave (ig,ng) = 4 rowtiles x 16 nt in
//   2 chunks of 8; ks unrolled x2, alternating B sets, imm-offset A reads.
// ---------------------------------------------------------------------------
__global__ __launch_bounds__(512, 2) void mm2_kernel(
    const float* __restrict__ hst,
    const float* __restrict__ epos,
    const unsigned char* __restrict__ ws,
    float* __restrict__ out)
{
    __shared__ __align__(16) unsigned char smem[LDS_SZ];

    const int s   = blockIdx.x >> 1;     // 256 scenes
    const int ih  = blockIdx.x & 1;      // i-half
    const int tid = threadIdx.x;
    const int w    = tid >> 6;           // 0..7
    const int l    = tid & 63;
    const int quad = l >> 4;
    const int jl   = l & 15;

    // ---- Phase A: HH via MFMA ----
    {
        union { unsigned u[4]; bf16x8 v; } afh[2];
        #pragma unroll
        for (int kb = 0; kb < 2; ++kb) {
            const float4* hp = (const float4*)(hst + (s * 16 + jl) * 64 + kb * 32 + quad * 8);
            float4 v0 = hp[0], v1 = hp[1];
            afh[kb].u[0] = pk_bf16(v0.x, v0.y);
            afh[kb].u[1] = pk_bf16(v0.z, v0.w);
            afh[kb].u[2] = pk_bf16(v1.x, v1.y);
            afh[kb].u[3] = pk_bf16(v1.z, v1.w);
        }
        const f32x4 fz = {0.f, 0.f, 0.f, 0.f};
        f32x4 acch[4] = {fz, fz, fz, fz};     // wave w -> k-cols w*64..+63
        #pragma unroll
        for (int kb = 0; kb < 2; ++kb) {
            #pragma unroll
            for (int ct = 0; ct < 4; ++ct) {
                bf16x8 bfr = *(const bf16x8*)(ws + BP1_OFF + ((((w * 4 + ct) * 2 + kb) * 64 + l) << 4));
                acch[ct] = __builtin_amdgcn_mfma_f32_16x16x32_bf16(afh[kb].v, bfr, acch[ct], 0, 0, 0);
            }
        }
        const float* SHg = (const float*)(ws + SH_OFF);
        const float* CBg = (const float*)(ws + CB_OFF);
        #pragma unroll
        for (int ct = 0; ct < 4; ++ct) {
            int col = (w * 4 + ct) * 16 + jl;        // k index
            float sh = SHg[col], cb = CBg[col];
            #pragma unroll
            for (int reg = 0; reg < 4; ++reg) {
                int j = quad * 4 + reg;
                float hv = fmaf(acch[ct][reg], sh, cb);
                *(unsigned short*)(smem + HH_LDS + j * 1024 + col * 2) = f2bf(hv);
            }
        }
    }
    __syncthreads();

    // ---- Phase B: construct Y1 (bf16, swizzled); MX/MY/pos from global ----
    {
        const int i2 = tid >> 8;           // 0..1  (4 i each)
        const int j  = (tid >> 4) & 15;
        const int kc = tid & 15;           // k0 = kc*32
        float rx[4], ry[4];
        float pjx = epos[s * 32 + j * 2], pjy = epos[s * 32 + j * 2 + 1];
        #pragma unroll
        for (int ii = 0; ii < 4; ++ii) {
            int ig_ = ih * 8 + i2 * 4 + ii;
            rx[ii] = pjx - epos[s * 32 + ig_ * 2];
            ry[ii] = pjy - epos[s * 32 + ig_ * 2 + 1];
        }
        const f32x2 zero2 = {0.f, 0.f};
        #pragma unroll
        for (int kk = 0; kk < 4; ++kk) {
            int k = kc * 32 + kk * 8;
            uint4 hh8 = *(const uint4*)(smem + HH_LDS + j * 1024 + k * 2);
            f32x4 mx0 = *(const f32x4*)(ws + MX_OFF + k * 4);
            f32x4 mx1 = *(const f32x4*)(ws + MX_OFF + k * 4 + 16);
            f32x4 my0 = *(const f32x4*)(ws + MY_OFF + k * 4);
            f32x4 my1 = *(const f32x4*)(ws + MY_OFF + k * 4 + 16);
            f32x2 mxp[4] = { {mx0[0],mx0[1]}, {mx0[2],mx0[3]}, {mx1[0],mx1[1]}, {mx1[2],mx1[3]} };
            f32x2 myp[4] = { {my0[0],my0[1]}, {my0[2],my0[3]}, {my1[0],my1[1]}, {my1[2],my1[3]} };
            f32x2 hhp[4];
            hhp[0][0] = bfbits2f(hh8.x << 16); hhp[0][1] = bfbits2f(hh8.x & 0xffff0000u);
            hhp[1][0] = bfbits2f(hh8.y << 16); hhp[1][1] = bfbits2f(hh8.y & 0xffff0000u);
            hhp[2][0] = bfbits2f(hh8.z << 16); hhp[2][1] = bfbits2f(hh8.z & 0xffff0000u);
            hhp[3][0] = bfbits2f(hh8.w << 16); hhp[3][1] = bfbits2f(hh8.w & 0xffff0000u);
            #pragma unroll
            for (int ii = 0; ii < 4; ++ii) {
                f32x2 rx2 = { rx[ii], rx[ii] };
                f32x2 ry2 = { ry[ii], ry[ii] };
                uint4 o;
                unsigned uu[4];
                #pragma unroll
                for (int p = 0; p < 4; ++p) {
                    f32x2 tt = __builtin_elementwise_fma(ry2, myp[p], hhp[p]);
                    tt = __builtin_elementwise_fma(rx2, mxp[p], tt);
                    tt = __builtin_elementwise_max(tt, zero2);
                    uu[p] = pk_bf16(tt[0], tt[1]);
                }
                o.x = uu[0]; o.y = uu[1]; o.z = uu[2]; o.w = uu[3];
                int r = (i2 * 4 + ii) * 16 + j;
                *(uint4*)(smem + Y1_LDS + y1off(r, kc * 4 + kk)) = o;
            }
        }
    }
    __syncthreads();

    // ---- Phase C: pure GEMM, no barriers ----
    const int ig = w & 1;                 // rowtiles i_local = ig*4 .. +3
    const int ng = w >> 1;                // nt group: 16 nt in 2 chunks of 8
    const float* A2 = (const float*)(ws + A2_OFF);
    const float* C2 = (const float*)(ws + C2_OFF);
    const f32x4 fzero = {0.f, 0.f, 0.f, 0.f};

    // A base offsets (even-ks); odd-ks = base ^ 64; per t add 128.
    int ab[4];
    #pragma unroll
    for (int rt = 0; rt < 4; ++rt) {
        int r = (ig * 4 + rt) * 16 + jl;
        ab[rt] = Y1_LDS + r * 1024 + ((quad ^ (r & 7)) << 4);
    }

    #pragma unroll 1
    for (int chunk = 0; chunk < 2; ++chunk) {
        const int ntbase = ng * 16 + chunk * 8;
        const unsigned char* bp0 = ws + BP2_OFF + (ntbase << 10) + (l << 4);
        // B addr = bp0 + ks*65536 + ct*1024

        f32x4 acc[4][8];
        #pragma unroll
        for (int rt = 0; rt < 4; ++rt)
            #pragma unroll
            for (int ct = 0; ct < 8; ++ct) acc[rt][ct] = fzero;

        bf16x8 b0[8], b1[8];
        #pragma unroll
        for (int ct = 0; ct < 8; ++ct)
            b0[ct] = *(const bf16x8*)(bp0 + ct * 1024);

        #pragma unroll 1
        for (int t = 0; t < 8; ++t) {
            // A frags for ks=2t (even) and 2t+1 (odd)
            bf16x8 ae[4], ao[4];
            #pragma unroll
            for (int rt = 0; rt < 4; ++rt)
                ae[rt] = *(const bf16x8*)(smem + (ab[rt] + t * 128));
            // B for ks=2t+1
            #pragma unroll
            for (int ct = 0; ct < 8; ++ct)
                b1[ct] = *(const bf16x8*)(bp0 + (2 * t + 1) * 65536 + ct * 1024);
            #pragma unroll
            for (int rt = 0; rt < 4; ++rt)
                ao[rt] = *(const bf16x8*)(smem + ((ab[rt] + t * 128) ^ 64));
            // MFMA even (uses b0)
            #pragma unroll
            for (int rt = 0; rt < 4; ++rt)
                #pragma unroll
                for (int ct = 0; ct < 8; ++ct)
                    acc[rt][ct] = __builtin_amdgcn_mfma_f32_16x16x32_bf16(ae[rt], b0[ct], acc[rt][ct], 0, 0, 0);
            // B for ks=2t+2 (t=7 overruns into BP1 region: harmless, unused)
            #pragma unroll
            for (int ct = 0; ct < 8; ++ct)
                b0[ct] = *(const bf16x8*)(bp0 + (2 * t + 2) * 65536 + ct * 1024);
            // MFMA odd (uses b1)
            #pragma unroll
            for (int rt = 0; rt < 4; ++rt)
                #pragma unroll
                for (int ct = 0; ct < 8; ++ct)
                    acc[rt][ct] = __builtin_amdgcn_mfma_f32_16x16x32_bf16(ao[rt], b1[ct], acc[rt][ct], 0, 0, 0);
        }

        // epilogue: bn2 + relu, maxpool over j (D rows), store fp32
        #pragma unroll
        for (int ct = 0; ct < 8; ++ct) {
            int col = (ntbase + ct) * 16 + jl;
            float a2 = A2[col], c2 = C2[col];
            #pragma unroll
            for (int rt = 0; rt < 4; ++rt) {
                float v0 = fmaxf(fmaf(acc[rt][ct][0], a2, c2), 0.f);
                float v1 = fmaxf(fmaf(acc[rt][ct][1], a2, c2), 0.f);
                float v2 = fmaxf(fmaf(acc[rt][ct][2], a2, c2), 0.f);
                float v3 = fmaxf(fmaf(acc[rt][ct][3], a2, c2), 0.f);
                float v = fmaxf(fmaxf(v0, v1), fmaxf(v2, v3));
                v = fmaxf(v, __shfl_xor(v, 16, 64));
                v = fmaxf(v, __shfl_xor(v, 32, 64));
                if (l < 16) {
                    int orow = s * 16 + ih * 8 + ig * 4 + rt;
                    __builtin_nontemporal_store(v, &out[orow * 1024 + col]);
                }
            }
        }
    }
}

extern "C" void kernel_launch(void* const* d_in, const int* in_sizes, int n_in,
                              void* d_out, int out_size, void* d_ws, size_t ws_size,
                              hipStream_t stream) {
    const float* hst  = (const float*)d_in[0];
    const float* epos = (const float*)d_in[1];
    const float* Wsp  = (const float*)d_in[4];
    const float* bsp  = (const float*)d_in[5];
    const float* Wp1  = (const float*)d_in[20];
    const float* bp1  = (const float*)d_in[21];
    const float* gp1  = (const float*)d_in[22];
    const float* btp1 = (const float*)d_in[23];
    const float* mp1  = (const float*)d_in[24];
    const float* vp1  = (const float*)d_in[25];
    const float* Wp2  = (const float*)d_in[26];
    const float* bp2  = (const float*)d_in[27];
    const float* gp2  = (const float*)d_in[28];
    const float* btp2 = (const float*)d_in[29];
    const float* mp2  = (const float*)d_in[30];
    const float* vp2  = (const float*)d_in[31];
    unsigned char* ws = (unsigned char*)d_ws;
    float* out = (float*)d_out;

    // 256 (Wp2 pack) + 16 (W1b pack) + 2 (k-consts) + 4 (A2/C2) = 278 blocks
    prep_pack_kernel<<<278, 256, 0, stream>>>(Wsp, bsp, Wp1, bp1, gp1, btp1, mp1, vp1,
                                              Wp2, bp2, gp2, btp2, mp2, vp2, ws);
    // 256 scenes x 2 i-halves, 512 threads (8 waves)
    mm2_kernel<<<512, 512, 0, stream>>>(hst, epos, ws, out);
}